// Round 4
// baseline (821.690 us; speedup 1.0000x reference)
//
#include <hip/hip_runtime.h>
#include <math.h>

#define HIDDEN 4096
#define MULT 4
#define HCD 16384      // MULT*HIDDEN
#define MIX 24
#define BB 4096

#define KA_THREADS 512
#define ROWS 32        // rows per block
#define HSPLIT 8       // h slices
#define HSLICE 512     // HIDDEN / HSPLIT
#define TILE_H 64
#define NTILES 8       // HSLICE / TILE_H
#define TILE_D 256     // MULT * TILE_H

// Main-loop barrier: LDS ordering only (lgkmcnt). Deliberately does NOT drain
// vmcnt, so res_cur global stores stay in flight across the barrier. Single
// asm block with memory clobber = full compiler fence (no LDS op can be
// hoisted/sunk across it). Control flow around every use is wave-uniform.
#define BAR() asm volatile("s_waitcnt lgkmcnt(0)\n\ts_barrier" ::: "memory")

// ---------- K0: transpose fn[24][16384] -> fnT[16384][24] ----------
__global__ __launch_bounds__(256) void k_transpose_fn(const float* __restrict__ fn,
                                                      float* __restrict__ fnT) {
    const int d = blockIdx.x * 256 + threadIdx.x;   // 0..16383
    float v[MIX];
#pragma unroll
    for (int m = 0; m < MIX; ++m) v[m] = fn[(size_t)m * HCD + d];
    float4* dst = (float4*)(fnT + (size_t)d * MIX);
#pragma unroll
    for (int m4 = 0; m4 < MIX / 4; ++m4)
        dst[m4] = make_float4(v[4*m4+0], v[4*m4+1], v[4*m4+2], v[4*m4+3]);
}

// ---------- KA: post-mapping + residual_cur write + sumsq + partial logits ----------
// grid = 1024 blocks (128 row-groups x 8 h-slices), 512 threads (8 waves).
// __launch_bounds__(512, 8): 8 waves/EU target -> 4 blocks/CU residency and
// regalloc pinned at <=64 VGPR (the previous ",4" declared only 2 blocks/CU —
// occupancy sat at ~43% in both the 64KB and 32KB LDS variants).
// Phase 1: thread (row1=tid>>4, q=tid&15) computes residual_cur for a 64-h tile,
//          writes global + XOR-swizzled LDS A[32 rows][256 d].
// Phase 2: wave wid covers 32 d of the tile; lane&31 = row; the two half-waves
//          duplicate the m-loop (fn stays wave-uniform scalar via readfirstlane).
__global__ __launch_bounds__(KA_THREADS, 8)
void k_main(const float* __restrict__ x_prev, const float* __restrict__ res_prev,
            const float* __restrict__ pm_prev, const float* __restrict__ comb_prev,
            const float* __restrict__ fnT, float* __restrict__ res_cur,
            float* __restrict__ part_lg, float* __restrict__ part_sq)
{
    __shared__ float A[ROWS * TILE_D];   // 32 KB, swizzled: phys = logical ^ ((row&7)<<2)
    const int tid  = threadIdx.x;
    const int rg   = blockIdx.x >> 3;   // row group 0..127
    const int hq   = blockIdx.x & 7;    // h slice 0..7
    const int row1 = tid >> 4;          // phase-1 row 0..31
    const int q    = tid & 15;
    const int b1   = rg * ROWS + row1;
    const int wid  = tid >> 6;          // wave 0..7
    const int lane = tid & 63;
    const int row2 = lane & 31;         // phase-2 row
    const int mh   = lane >> 5;         // half-wave id (0/1)

    float comb[MULT][MULT], pm[MULT];
#pragma unroll
    for (int i = 0; i < MULT; ++i) {
        pm[i] = pm_prev[(size_t)b1 * MULT + i];
#pragma unroll
        for (int j = 0; j < MULT; ++j)
            comb[i][j] = comb_prev[(size_t)b1 * 16 + i * 4 + j];
    }

    float acc[MIX];
#pragma unroll
    for (int m = 0; m < MIX; ++m) acc[m] = 0.f;
    float ssq = 0.f;

    const int sw1   = (row1 & 7) << 2;
    const int sw2   = (row2 & 7) << 2;
    const int i_str = wid >> 1;
    const int hoffb = (wid & 1) * 32;

#pragma unroll 1
    for (int t = 0; t < NTILES; ++t) {
        const int h0 = hq * HSLICE + t * TILE_H;
        // ---- phase 1 ----
        const size_t gh = (size_t)h0 + q * 4;           // 16 q-threads cover 64 h
        const float4 xv = *(const float4*)(x_prev + (size_t)b1 * HIDDEN + gh);
        float4 rv[MULT];
#pragma unroll
        for (int j = 0; j < MULT; ++j)
            rv[j] = *(const float4*)(res_prev + ((size_t)b1 * MULT + j) * HIDDEN + gh);
#pragma unroll
        for (int i = 0; i < MULT; ++i) {
            float4 r;
            r.x = pm[i] * xv.x; r.y = pm[i] * xv.y;
            r.z = pm[i] * xv.z; r.w = pm[i] * xv.w;
#pragma unroll
            for (int j = 0; j < MULT; ++j) {
                r.x += comb[i][j] * rv[j].x; r.y += comb[i][j] * rv[j].y;
                r.z += comb[i][j] * rv[j].z; r.w += comb[i][j] * rv[j].w;
            }
            *(float4*)(res_cur + ((size_t)b1 * MULT + i) * HIDDEN + gh) = r;
            ssq += r.x*r.x + r.y*r.y + r.z*r.z + r.w*r.w;
            const int dl = i * TILE_H + q * 4;          // logical d in tile, 0..255
            *(float4*)(&A[row1 * TILE_D + (dl ^ sw1)]) = r;
        }
        BAR();
        // ---- phase 2: logits partial accumulate (half-waves duplicate m-range) ----
#pragma unroll
        for (int k = 0; k < 8; ++k) {
            const int dl = wid * 32 + k * 4;
            const float4 av = *(const float4*)(&A[row2 * TILE_D + (dl ^ sw2)]);
            const int dg = i_str * HIDDEN + h0 + hoffb + k * 4;   // wave-uniform
            const float* fp = fnT + (size_t)__builtin_amdgcn_readfirstlane(dg) * MIX;
#pragma unroll
            for (int m = 0; m < MIX; ++m) acc[m] += av.x * fp[m];
#pragma unroll
            for (int m = 0; m < MIX; ++m) acc[m] += av.y * fp[MIX + m];
#pragma unroll
            for (int m = 0; m < MIX; ++m) acc[m] += av.z * fp[2 * MIX + m];
#pragma unroll
            for (int m = 0; m < MIX; ++m) acc[m] += av.w * fp[3 * MIX + m];
        }
        BAR();
    }

    // ---- sumsq: reduce the 16 q-threads of each row (adjacent lanes) ----
    ssq += __shfl_down(ssq, 8);
    ssq += __shfl_down(ssq, 4);
    ssq += __shfl_down(ssq, 2);
    ssq += __shfl_down(ssq, 1);
    if (q == 0) part_sq[(size_t)hq * BB + b1] = ssq;

    // ---- logits: cross-wave reduce in LDS. P[(row2*8+wid)*24 + mh*12 + j],
    //      half-wave mh stores m-range [mh*12, mh*12+12)  (32*8*24 = 6144 floats) ----
    {
        const int base = (row2 * 8 + wid) * 24 + mh * 12;
        if (mh == 0) {
#pragma unroll
            for (int j4 = 0; j4 < 3; ++j4)
                *(float4*)(&A[base + j4 * 4]) =
                    make_float4(acc[j4*4+0], acc[j4*4+1], acc[j4*4+2], acc[j4*4+3]);
        } else {
#pragma unroll
            for (int j4 = 0; j4 < 3; ++j4)
                *(float4*)(&A[base + j4 * 4]) =
                    make_float4(acc[12+j4*4+0], acc[12+j4*4+1], acc[12+j4*4+2], acc[12+j4*4+3]);
        }
    }
    __syncthreads();   // cold path: one full drain at the end is fine
#pragma unroll 1
    for (int it = tid; it < ROWS * MIX; it += KA_THREADS) {   // 768 items
        const int row = it / MIX;
        const int m   = it - row * MIX;
        float s = 0.f;
#pragma unroll
        for (int w = 0; w < 8; ++w) s += A[(row * 8 + w) * 24 + m];
        part_lg[((size_t)hq * BB + rg * ROWS + row) * MIX + m] = s;
    }
}

// ---------- KB: finalize per-row scalars (rms, softmax, sigmoid, Sinkhorn) ----------
__global__ __launch_bounds__(256) void k_finalize(
        const float* __restrict__ part_lg, const float* __restrict__ part_sq,
        const float* __restrict__ basep, const float* __restrict__ scale,
        float* __restrict__ post_mix, float* __restrict__ comb_out,
        float* __restrict__ h_pre)
{
    const int row = blockIdx.x * 256 + threadIdx.x;   // 0..4095
    float lg[MIX];
#pragma unroll
    for (int m = 0; m < MIX; ++m) lg[m] = 0.f;
    float ssq = 0.f;
#pragma unroll
    for (int w = 0; w < HSPLIT; ++w) {
        const float* p = part_lg + ((size_t)w * BB + row) * MIX;
#pragma unroll
        for (int m = 0; m < MIX; ++m) lg[m] += p[m];
        ssq += part_sq[(size_t)w * BB + row];
    }
    const float rms = sqrtf(ssq * (1.0f / (float)HCD) + 1e-6f);
    const float inv = 1.0f / rms;
    const float s0 = scale[0], s1 = scale[1], s2 = scale[2];

    float pre[4], post[4], rr[16];
#pragma unroll
    for (int i = 0; i < 4; ++i)  pre[i]  = lg[i]     * inv * s0 + basep[i];
#pragma unroll
    for (int i = 0; i < 4; ++i)  post[i] = lg[4 + i] * inv * s1 + basep[4 + i];
#pragma unroll
    for (int k = 0; k < 16; ++k) rr[k]   = lg[8 + k] * inv * s2 + basep[8 + k];

    // softmax (stable) -> h_pre
    const float mx = fmaxf(fmaxf(pre[0], pre[1]), fmaxf(pre[2], pre[3]));
    float e[4], es = 0.f;
#pragma unroll
    for (int i = 0; i < 4; ++i) { e[i] = expf(pre[i] - mx); es += e[i]; }
    const float esr = 1.0f / es;
    float4 hp = make_float4(e[0]*esr, e[1]*esr, e[2]*esr, e[3]*esr);
    *(float4*)(h_pre + (size_t)row * 4) = hp;

    // sigmoid -> post_mix_cur
    float4 pmv = make_float4(1.f/(1.f+expf(-post[0])), 1.f/(1.f+expf(-post[1])),
                             1.f/(1.f+expf(-post[2])), 1.f/(1.f+expf(-post[3])));
    *(float4*)(post_mix + (size_t)row * 4) = pmv;

    // Sinkhorn-Knopp, 10 iters: row-normalize then col-normalize
    // (reciprocal-multiply: shortens the serial dependence chain vs 4 divides)
    float M[16];
#pragma unroll
    for (int k = 0; k < 16; ++k) M[k] = expf(rr[k]);
#pragma unroll 1
    for (int it = 0; it < 10; ++it) {
#pragma unroll
        for (int i = 0; i < 4; ++i) {
            const float rs = 1.0f /
                (M[i*4+0] + M[i*4+1] + M[i*4+2] + M[i*4+3] + 1e-6f);
#pragma unroll
            for (int j = 0; j < 4; ++j) M[i*4+j] *= rs;
        }
#pragma unroll
        for (int j = 0; j < 4; ++j) {
            const float cs = 1.0f /
                (M[j] + M[4+j] + M[8+j] + M[12+j] + 1e-6f);
#pragma unroll
            for (int i = 0; i < 4; ++i) M[i*4+j] *= cs;
        }
    }
#pragma unroll
    for (int m4 = 0; m4 < 4; ++m4)
        *(float4*)(comb_out + (size_t)row * 16 + m4 * 4) =
            make_float4(M[4*m4+0], M[4*m4+1], M[4*m4+2], M[4*m4+3]);
}

// ---------- KC: layer_input[b,h] = sum_i h_pre[b,i] * residual_cur[b,i,h] ----------
__global__ __launch_bounds__(256) void k_layer(const float* __restrict__ res_cur,
                                               const float* __restrict__ h_pre,
                                               float* __restrict__ out)
{
    const int g = blockIdx.x * 256 + threadIdx.x;   // float4 index, 4,194,304 total
    const int b = g >> 10;
    const int c = g & 1023;
    const float4 hp = *(const float4*)(h_pre + (size_t)b * 4);
    const float hpa[4] = {hp.x, hp.y, hp.z, hp.w};
    const float* basep = res_cur + (size_t)b * MULT * HIDDEN + (size_t)c * 4;
    float4 o; o.x = o.y = o.z = o.w = 0.f;
#pragma unroll
    for (int i = 0; i < 4; ++i) {
        const float4 v = *(const float4*)(basep + (size_t)i * HIDDEN);
        o.x += hpa[i]*v.x; o.y += hpa[i]*v.y; o.z += hpa[i]*v.z; o.w += hpa[i]*v.w;
    }
    *(float4*)(out + (size_t)b * HIDDEN + (size_t)c * 4) = o;
}

extern "C" void kernel_launch(void* const* d_in, const int* in_sizes, int n_in,
                              void* d_out, int out_size, void* d_ws, size_t ws_size,
                              hipStream_t stream) {
    const float* x_prev    = (const float*)d_in[0];
    const float* res_prev  = (const float*)d_in[1];
    const float* pm_prev   = (const float*)d_in[2];
    const float* comb_prev = (const float*)d_in[3];
    const float* fn        = (const float*)d_in[4];
    const float* base      = (const float*)d_in[5];
    const float* scale     = (const float*)d_in[6];

    float* out = (float*)d_out;
    float* res_cur  = out;                                   // 4096*4*4096
    float* post_mix = out + 67108864;                        // 4096*4
    float* comb_out = out + 67108864 + 16384;                // 4096*16
    float* layer_in = out + 67108864 + 16384 + 65536;        // 4096*4096

    float* ws = (float*)d_ws;
    float* fnT     = ws;                                     // 393,216 floats
    float* part_lg = ws + 393216;                            // 8*4096*24 = 786,432
    float* part_sq = ws + 393216 + 786432;                   // 8*4096   =  32,768
    float* h_pre   = ws + 393216 + 786432 + 32768;           // 4096*4   =  16,384

    k_transpose_fn<<<HCD / 256, 256, 0, stream>>>(fn, fnT);
    k_main<<<(BB / ROWS) * HSPLIT, KA_THREADS, 0, stream>>>(
        x_prev, res_prev, pm_prev, comb_prev, fnT, res_cur, part_lg, part_sq);
    k_finalize<<<BB / 256, 256, 0, stream>>>(part_lg, part_sq, base, scale,
                                             post_mix, comb_out, h_pre);
    k_layer<<<(BB * HIDDEN / 4) / 256, 256, 0, stream>>>(res_cur, h_pre, layer_in);
}

// Round 5
// 736.025 us; speedup vs baseline: 1.1164x; 1.1164x over previous
//
#include <hip/hip_runtime.h>
#include <math.h>

#define HIDDEN 4096
#define MULT 4
#define HCD 16384      // MULT*HIDDEN
#define MIX 24
#define BB 4096

#define KA_THREADS 512
#define ROWS 64        // rows per block
#define HSPLIT 16      // h slices
#define HSLICE 256     // HIDDEN / HSPLIT
#define TILE_H 32
#define NTILES 8       // HSLICE / TILE_H
#define TILE_D 128     // MULT * TILE_H
#define LG_LDS (ROWS * 8 * MIX)   // 12288 floats = 48 KB (logit-reduce region)

// Main-loop barrier: LDS ordering only (lgkmcnt). Deliberately does NOT drain
// vmcnt, so res_cur global stores stay in flight across the barrier. Single
// asm block with memory clobber = full compiler fence. All uses are in
// wave-uniform control flow. (Verified correct in round 4.)
#define BAR() asm volatile("s_waitcnt lgkmcnt(0)\n\ts_barrier" ::: "memory")

// ---------- K0: transpose fn[24][16384] -> fnT[16384][24] ----------
__global__ __launch_bounds__(256) void k_transpose_fn(const float* __restrict__ fn,
                                                      float* __restrict__ fnT) {
    const int d = blockIdx.x * 256 + threadIdx.x;   // 0..16383
    float v[MIX];
#pragma unroll
    for (int m = 0; m < MIX; ++m) v[m] = fn[(size_t)m * HCD + d];
    float4* dst = (float4*)(fnT + (size_t)d * MIX);
#pragma unroll
    for (int m4 = 0; m4 < MIX / 4; ++m4)
        dst[m4] = make_float4(v[4*m4+0], v[4*m4+1], v[4*m4+2], v[4*m4+3]);
}

// ---------- KA: post-mapping + residual_cur write + sumsq + partial logits ----------
// grid = 1024 blocks (64 row-groups x 16 h-slices), 512 threads (8 waves).
// __launch_bounds__(512, 6): VGPR cap ~85 (natural demand ~60-75 -> NO spills;
// the (512,8) attempt capped at 64, collapsed to 32 VGPR and spilled ~750 MB
// of scratch traffic). 48 KB LDS -> 3 blocks/CU = 24 waves = 75% occupancy,
// exactly the 6-waves/EU declaration.
// Tile = 64 rows x 128 d (TILE_H=32). Phase 2 now has lane=row for ALL 64
// lanes (no half-wave duplication: round-3's version computed 24 dots/thread
// and discarded 12). Each wave covers 16 d; fn values stay wave-uniform
// (readfirstlane -> s_load broadcast).
__global__ __launch_bounds__(KA_THREADS, 6)
void k_main(const float* __restrict__ x_prev, const float* __restrict__ res_prev,
            const float* __restrict__ pm_prev, const float* __restrict__ comb_prev,
            const float* __restrict__ fnT, float* __restrict__ res_cur,
            float* __restrict__ part_lg, float* __restrict__ part_sq)
{
    __shared__ float A[LG_LDS];   // 48 KB; phase loop uses first 32 KB,
                                  // final logit reduce uses all 48 KB
    const int tid  = threadIdx.x;
    const int rg   = blockIdx.x >> 4;   // row group 0..63
    const int hq   = blockIdx.x & 15;   // h slice 0..15
    const int row1 = tid >> 3;          // phase-1 row 0..63
    const int q    = tid & 7;           // 8 threads x float4 = 32 h
    const int b1   = rg * ROWS + row1;
    const int wid  = tid >> 6;          // wave 0..7
    const int lane = tid & 63;          // phase-2 row (all 64 distinct)

    float comb[MULT][MULT], pm[MULT];
#pragma unroll
    for (int i = 0; i < MULT; ++i) {
        pm[i] = pm_prev[(size_t)b1 * MULT + i];
#pragma unroll
        for (int j = 0; j < MULT; ++j)
            comb[i][j] = comb_prev[(size_t)b1 * 16 + i * 4 + j];
    }

    float acc[MIX];
#pragma unroll
    for (int m = 0; m < MIX; ++m) acc[m] = 0.f;
    float ssq = 0.f;

    const int sw1   = (row1 & 7) << 2;
    const int sw2   = (lane & 7) << 2;
    const int i_str = wid >> 1;          // i stream 0..3 (2 waves per i)
    const int hoffb = (wid & 1) * 16;    // 16-h half within the 32-h tile

#pragma unroll 1
    for (int t = 0; t < NTILES; ++t) {
        const int h0 = hq * HSLICE + t * TILE_H;
        // ---- phase 1: residual_cur for 64 rows x 32 h ----
        const size_t gh = (size_t)h0 + q * 4;
        const float4 xv = *(const float4*)(x_prev + (size_t)b1 * HIDDEN + gh);
        float4 rv[MULT];
#pragma unroll
        for (int j = 0; j < MULT; ++j)
            rv[j] = *(const float4*)(res_prev + ((size_t)b1 * MULT + j) * HIDDEN + gh);
#pragma unroll
        for (int i = 0; i < MULT; ++i) {
            float4 r;
            r.x = pm[i] * xv.x; r.y = pm[i] * xv.y;
            r.z = pm[i] * xv.z; r.w = pm[i] * xv.w;
#pragma unroll
            for (int j = 0; j < MULT; ++j) {
                r.x += comb[i][j] * rv[j].x; r.y += comb[i][j] * rv[j].y;
                r.z += comb[i][j] * rv[j].z; r.w += comb[i][j] * rv[j].w;
            }
            *(float4*)(res_cur + ((size_t)b1 * MULT + i) * HIDDEN + gh) = r;
            ssq += r.x*r.x + r.y*r.y + r.z*r.z + r.w*r.w;
            const int dl = i * TILE_H + q * 4;          // logical d in tile, 0..127
            *(float4*)(&A[row1 * TILE_D + (dl ^ sw1)]) = r;
        }
        BAR();
        // ---- phase 2: logits partial accumulate (wave covers 16 d, lane=row) ----
#pragma unroll
        for (int k = 0; k < 4; ++k) {
            const int dl = wid * 16 + k * 4;
            const float4 av = *(const float4*)(&A[lane * TILE_D + (dl ^ sw2)]);
            const int dg = i_str * HIDDEN + h0 + hoffb + k * 4;   // wave-uniform
            const float* fp = fnT + (size_t)__builtin_amdgcn_readfirstlane(dg) * MIX;
#pragma unroll
            for (int m = 0; m < MIX; ++m) acc[m] += av.x * fp[m];
#pragma unroll
            for (int m = 0; m < MIX; ++m) acc[m] += av.y * fp[MIX + m];
#pragma unroll
            for (int m = 0; m < MIX; ++m) acc[m] += av.z * fp[2 * MIX + m];
#pragma unroll
            for (int m = 0; m < MIX; ++m) acc[m] += av.w * fp[3 * MIX + m];
        }
        BAR();
    }

    // ---- sumsq: reduce the 8 q-threads of each row (adjacent lanes) ----
    ssq += __shfl_down(ssq, 4);
    ssq += __shfl_down(ssq, 2);
    ssq += __shfl_down(ssq, 1);
    if (q == 0) part_sq[(size_t)hq * BB + b1] = ssq;

    // ---- logits: cross-wave reduce in LDS. P[(row*8 + wid)*24 + m],
    //      64 rows x 8 waves x 24 m = 12288 floats = full 48 KB ----
    {
        const int base = (lane * 8 + wid) * MIX;
#pragma unroll
        for (int m4 = 0; m4 < 6; ++m4)
            *(float4*)(&A[base + m4 * 4]) =
                make_float4(acc[4*m4+0], acc[4*m4+1], acc[4*m4+2], acc[4*m4+3]);
    }
    BAR();
#pragma unroll 1
    for (int it = tid; it < ROWS * MIX; it += KA_THREADS) {   // 1536 items, 3 iters
        const int row = it / MIX;
        const int m   = it - row * MIX;
        float s = 0.f;
#pragma unroll
        for (int w = 0; w < 8; ++w) s += A[(row * 8 + w) * MIX + m];
        part_lg[((size_t)hq * BB + rg * ROWS + row) * MIX + m] = s;
    }
}

// ---------- KB: finalize per-row scalars (rms, softmax, sigmoid, Sinkhorn) ----------
__global__ __launch_bounds__(256) void k_finalize(
        const float* __restrict__ part_lg, const float* __restrict__ part_sq,
        const float* __restrict__ basep, const float* __restrict__ scale,
        float* __restrict__ post_mix, float* __restrict__ comb_out,
        float* __restrict__ h_pre)
{
    const int row = blockIdx.x * 256 + threadIdx.x;   // 0..4095
    float lg[MIX];
#pragma unroll
    for (int m = 0; m < MIX; ++m) lg[m] = 0.f;
    float ssq = 0.f;
#pragma unroll
    for (int w = 0; w < HSPLIT; ++w) {
        const float* p = part_lg + ((size_t)w * BB + row) * MIX;
#pragma unroll
        for (int m = 0; m < MIX; ++m) lg[m] += p[m];
        ssq += part_sq[(size_t)w * BB + row];
    }
    const float rms = sqrtf(ssq * (1.0f / (float)HCD) + 1e-6f);
    const float inv = 1.0f / rms;
    const float s0 = scale[0], s1 = scale[1], s2 = scale[2];

    float pre[4], post[4], rr[16];
#pragma unroll
    for (int i = 0; i < 4; ++i)  pre[i]  = lg[i]     * inv * s0 + basep[i];
#pragma unroll
    for (int i = 0; i < 4; ++i)  post[i] = lg[4 + i] * inv * s1 + basep[4 + i];
#pragma unroll
    for (int k = 0; k < 16; ++k) rr[k]   = lg[8 + k] * inv * s2 + basep[8 + k];

    // softmax (stable) -> h_pre
    const float mx = fmaxf(fmaxf(pre[0], pre[1]), fmaxf(pre[2], pre[3]));
    float e[4], es = 0.f;
#pragma unroll
    for (int i = 0; i < 4; ++i) { e[i] = expf(pre[i] - mx); es += e[i]; }
    const float esr = 1.0f / es;
    float4 hp = make_float4(e[0]*esr, e[1]*esr, e[2]*esr, e[3]*esr);
    *(float4*)(h_pre + (size_t)row * 4) = hp;

    // sigmoid -> post_mix_cur
    float4 pmv = make_float4(1.f/(1.f+expf(-post[0])), 1.f/(1.f+expf(-post[1])),
                             1.f/(1.f+expf(-post[2])), 1.f/(1.f+expf(-post[3])));
    *(float4*)(post_mix + (size_t)row * 4) = pmv;

    // Sinkhorn-Knopp, 10 iters: row-normalize then col-normalize
    float M[16];
#pragma unroll
    for (int k = 0; k < 16; ++k) M[k] = expf(rr[k]);
#pragma unroll 1
    for (int it = 0; it < 10; ++it) {
#pragma unroll
        for (int i = 0; i < 4; ++i) {
            const float rs = 1.0f /
                (M[i*4+0] + M[i*4+1] + M[i*4+2] + M[i*4+3] + 1e-6f);
#pragma unroll
            for (int j = 0; j < 4; ++j) M[i*4+j] *= rs;
        }
#pragma unroll
        for (int j = 0; j < 4; ++j) {
            const float cs = 1.0f /
                (M[j] + M[4+j] + M[8+j] + M[12+j] + 1e-6f);
#pragma unroll
            for (int i = 0; i < 4; ++i) M[i*4+j] *= cs;
        }
    }
#pragma unroll
    for (int m4 = 0; m4 < 4; ++m4)
        *(float4*)(comb_out + (size_t)row * 16 + m4 * 4) =
            make_float4(M[4*m4+0], M[4*m4+1], M[4*m4+2], M[4*m4+3]);
}

// ---------- KC: layer_input[b,h] = sum_i h_pre[b,i] * residual_cur[b,i,h] ----------
__global__ __launch_bounds__(256) void k_layer(const float* __restrict__ res_cur,
                                               const float* __restrict__ h_pre,
                                               float* __restrict__ out)
{
    const int g = blockIdx.x * 256 + threadIdx.x;   // float4 index, 4,194,304 total
    const int b = g >> 10;
    const int c = g & 1023;
    const float4 hp = *(const float4*)(h_pre + (size_t)b * 4);
    const float hpa[4] = {hp.x, hp.y, hp.z, hp.w};
    const float* basep = res_cur + (size_t)b * MULT * HIDDEN + (size_t)c * 4;
    float4 o; o.x = o.y = o.z = o.w = 0.f;
#pragma unroll
    for (int i = 0; i < 4; ++i) {
        const float4 v = *(const float4*)(basep + (size_t)i * HIDDEN);
        o.x += hpa[i]*v.x; o.y += hpa[i]*v.y; o.z += hpa[i]*v.z; o.w += hpa[i]*v.w;
    }
    *(float4*)(out + (size_t)b * HIDDEN + (size_t)c * 4) = o;
}

extern "C" void kernel_launch(void* const* d_in, const int* in_sizes, int n_in,
                              void* d_out, int out_size, void* d_ws, size_t ws_size,
                              hipStream_t stream) {
    const float* x_prev    = (const float*)d_in[0];
    const float* res_prev  = (const float*)d_in[1];
    const float* pm_prev   = (const float*)d_in[2];
    const float* comb_prev = (const float*)d_in[3];
    const float* fn        = (const float*)d_in[4];
    const float* base      = (const float*)d_in[5];
    const float* scale     = (const float*)d_in[6];

    float* out = (float*)d_out;
    float* res_cur  = out;                                   // 4096*4*4096
    float* post_mix = out + 67108864;                        // 4096*4
    float* comb_out = out + 67108864 + 16384;                // 4096*16
    float* layer_in = out + 67108864 + 16384 + 65536;        // 4096*4096

    float* ws = (float*)d_ws;
    float* fnT     = ws;                                     // 393,216 floats
    float* part_lg = ws + 393216;                            // 16*4096*24 = 1,572,864
    float* part_sq = ws + 393216 + 1572864;                  // 16*4096   =    65,536
    float* h_pre   = ws + 393216 + 1572864 + 65536;          // 4096*4    =    16,384

    k_transpose_fn<<<HCD / 256, 256, 0, stream>>>(fn, fnT);
    k_main<<<(BB / ROWS) * HSPLIT, KA_THREADS, 0, stream>>>(
        x_prev, res_prev, pm_prev, comb_prev, fnT, res_cur, part_lg, part_sq);
    k_finalize<<<BB / 256, 256, 0, stream>>>(part_lg, part_sq, base, scale,
                                             post_mix, comb_out, h_pre);
    k_layer<<<(BB * HIDDEN / 4) / 256, 256, 0, stream>>>(res_cur, h_pre, layer_in);
}

// Round 6
// 675.688 us; speedup vs baseline: 1.2161x; 1.0893x over previous
//
#include <hip/hip_runtime.h>
#include <math.h>

#define HIDDEN 4096
#define MULT 4
#define HCD 16384      // MULT*HIDDEN
#define MIX 24
#define BB 4096

#define KA_THREADS 512
#define ROWS 32        // rows per block
#define HSPLIT 8       // h slices
#define HSLICE 512     // HIDDEN / HSPLIT
#define TILE_H 64
#define NTILES 8       // HSLICE / TILE_H
#define TILE_D 256     // MULT * TILE_H

// Main-loop barrier: LDS ordering only (lgkmcnt). Does NOT drain vmcnt, so
// res_cur global stores stay in flight across the barrier. Verified correct
// (passed) in rounds 4 and 5. Single asm block with memory clobber = full
// compiler fence; all uses are in wave-uniform control flow.
#define BAR() asm volatile("s_waitcnt lgkmcnt(0)\n\ts_barrier" ::: "memory")

// ---------- K0: transpose fn[24][16384] -> fnT[16384][24] ----------
__global__ __launch_bounds__(256) void k_transpose_fn(const float* __restrict__ fn,
                                                      float* __restrict__ fnT) {
    const int d = blockIdx.x * 256 + threadIdx.x;   // 0..16383
    float v[MIX];
#pragma unroll
    for (int m = 0; m < MIX; ++m) v[m] = fn[(size_t)m * HCD + d];
    float4* dst = (float4*)(fnT + (size_t)d * MIX);
#pragma unroll
    for (int m4 = 0; m4 < MIX / 4; ++m4)
        dst[m4] = make_float4(v[4*m4+0], v[4*m4+1], v[4*m4+2], v[4*m4+3]);
}

// ---------- KA: post-mapping + residual_cur write + sumsq + partial logits ----------
// EXACT round-3 structure (fastest verified: 223 us, VGPR 60, no spill),
// with lgkm-only BAR() instead of __syncthreads (verified rounds 4/5).
// launch_bounds 2nd arg LAW (measured r3/r4/r5): VGPR cap = ~256/arg.
// arg=4 -> cap 64 -> natural 60, no spill. arg>=6 spills this kernel. Keep 4.
__global__ __launch_bounds__(KA_THREADS, 4)
void k_main(const float* __restrict__ x_prev, const float* __restrict__ res_prev,
            const float* __restrict__ pm_prev, const float* __restrict__ comb_prev,
            const float* __restrict__ fnT, float* __restrict__ res_cur,
            float* __restrict__ part_lg, float* __restrict__ part_sq)
{
    __shared__ float A[ROWS * TILE_D];   // 32 KB, swizzled: phys = logical ^ ((row&7)<<2)
    const int tid  = threadIdx.x;
    const int rg   = blockIdx.x >> 3;   // row group 0..127
    const int hq   = blockIdx.x & 7;    // h slice 0..7
    const int row1 = tid >> 4;          // phase-1 row 0..31
    const int q    = tid & 15;
    const int b1   = rg * ROWS + row1;
    const int wid  = tid >> 6;          // wave 0..7
    const int lane = tid & 63;
    const int row2 = lane & 31;         // phase-2 row
    const int mh   = lane >> 5;         // half-wave id (0/1)

    float comb[MULT][MULT], pm[MULT];
#pragma unroll
    for (int i = 0; i < MULT; ++i) {
        pm[i] = pm_prev[(size_t)b1 * MULT + i];
#pragma unroll
        for (int j = 0; j < MULT; ++j)
            comb[i][j] = comb_prev[(size_t)b1 * 16 + i * 4 + j];
    }

    float acc[MIX];
#pragma unroll
    for (int m = 0; m < MIX; ++m) acc[m] = 0.f;
    float ssq = 0.f;

    const int sw1   = (row1 & 7) << 2;
    const int sw2   = (row2 & 7) << 2;
    const int i_str = wid >> 1;
    const int hoffb = (wid & 1) * 32;

#pragma unroll 1
    for (int t = 0; t < NTILES; ++t) {
        const int h0 = hq * HSLICE + t * TILE_H;
        // ---- phase 1 ----
        const size_t gh = (size_t)h0 + q * 4;           // 16 q-threads cover 64 h
        const float4 xv = *(const float4*)(x_prev + (size_t)b1 * HIDDEN + gh);
        float4 rv[MULT];
#pragma unroll
        for (int j = 0; j < MULT; ++j)
            rv[j] = *(const float4*)(res_prev + ((size_t)b1 * MULT + j) * HIDDEN + gh);
#pragma unroll
        for (int i = 0; i < MULT; ++i) {
            float4 r;
            r.x = pm[i] * xv.x; r.y = pm[i] * xv.y;
            r.z = pm[i] * xv.z; r.w = pm[i] * xv.w;
#pragma unroll
            for (int j = 0; j < MULT; ++j) {
                r.x += comb[i][j] * rv[j].x; r.y += comb[i][j] * rv[j].y;
                r.z += comb[i][j] * rv[j].z; r.w += comb[i][j] * rv[j].w;
            }
            *(float4*)(res_cur + ((size_t)b1 * MULT + i) * HIDDEN + gh) = r;
            ssq += r.x*r.x + r.y*r.y + r.z*r.z + r.w*r.w;
            const int dl = i * TILE_H + q * 4;          // logical d in tile, 0..255
            *(float4*)(&A[row1 * TILE_D + (dl ^ sw1)]) = r;
        }
        BAR();
        // ---- phase 2: logits partial accumulate (half-waves duplicate m-range) ----
#pragma unroll
        for (int k = 0; k < 8; ++k) {
            const int dl = wid * 32 + k * 4;
            const float4 av = *(const float4*)(&A[row2 * TILE_D + (dl ^ sw2)]);
            const int dg = i_str * HIDDEN + h0 + hoffb + k * 4;   // wave-uniform
            const float* fp = fnT + (size_t)__builtin_amdgcn_readfirstlane(dg) * MIX;
#pragma unroll
            for (int m = 0; m < MIX; ++m) acc[m] += av.x * fp[m];
#pragma unroll
            for (int m = 0; m < MIX; ++m) acc[m] += av.y * fp[MIX + m];
#pragma unroll
            for (int m = 0; m < MIX; ++m) acc[m] += av.z * fp[2 * MIX + m];
#pragma unroll
            for (int m = 0; m < MIX; ++m) acc[m] += av.w * fp[3 * MIX + m];
        }
        BAR();
    }

    // ---- sumsq: reduce the 16 q-threads of each row (adjacent lanes) ----
    ssq += __shfl_down(ssq, 8);
    ssq += __shfl_down(ssq, 4);
    ssq += __shfl_down(ssq, 2);
    ssq += __shfl_down(ssq, 1);
    if (q == 0) part_sq[(size_t)hq * BB + b1] = ssq;

    // ---- logits: cross-wave reduce in LDS. P[(row2*8+wid)*24 + mh*12 + j],
    //      half-wave mh stores m-range [mh*12, mh*12+12)  (32*8*24 = 6144 floats) ----
    {
        const int base = (row2 * 8 + wid) * 24 + mh * 12;
        if (mh == 0) {
#pragma unroll
            for (int j4 = 0; j4 < 3; ++j4)
                *(float4*)(&A[base + j4 * 4]) =
                    make_float4(acc[j4*4+0], acc[j4*4+1], acc[j4*4+2], acc[j4*4+3]);
        } else {
#pragma unroll
            for (int j4 = 0; j4 < 3; ++j4)
                *(float4*)(&A[base + j4 * 4]) =
                    make_float4(acc[12+j4*4+0], acc[12+j4*4+1], acc[12+j4*4+2], acc[12+j4*4+3]);
        }
    }
    BAR();
#pragma unroll 1
    for (int it = tid; it < ROWS * MIX; it += KA_THREADS) {   // 768 items
        const int row = it / MIX;
        const int m   = it - row * MIX;
        float s = 0.f;
#pragma unroll
        for (int w = 0; w < 8; ++w) s += A[(row * 8 + w) * 24 + m];
        part_lg[((size_t)hq * BB + rg * ROWS + row) * MIX + m] = s;
    }
}

// ---------- KB+KC fused: per-row finalize + layer_input ----------
// grid = 4096 blocks (one per batch row) x 256 threads.
// Replaces the 16-block latency-bound k_finalize and the separate k_layer:
// res_cur row is read once per block, soon after k_main wrote it (L3-warm),
// and the h_pre global roundtrip disappears.
__global__ __launch_bounds__(256) void k_post(
        const float* __restrict__ part_lg, const float* __restrict__ part_sq,
        const float* __restrict__ basep, const float* __restrict__ scale,
        const float* __restrict__ res_cur,
        float* __restrict__ post_mix, float* __restrict__ comb_out,
        float* __restrict__ layer_in)
{
    const int b   = blockIdx.x;       // row 0..4095
    const int tid = threadIdx.x;
    __shared__ float red[MIX + 1];    // 24 logit sums + ssq
    __shared__ float hp_s[4];

    if (tid < MIX) {
        float s = 0.f;
#pragma unroll
        for (int w = 0; w < HSPLIT; ++w)
            s += part_lg[((size_t)w * BB + b) * MIX + tid];
        red[tid] = s;
    } else if (tid == MIX) {
        float s = 0.f;
#pragma unroll
        for (int w = 0; w < HSPLIT; ++w) s += part_sq[(size_t)w * BB + b];
        red[MIX] = s;
    }
    __syncthreads();

    if (tid == 0) {
        const float rms = sqrtf(red[MIX] * (1.0f / (float)HCD) + 1e-6f);
        const float inv = 1.0f / rms;
        const float s0 = scale[0], s1 = scale[1], s2 = scale[2];

        float pre[4], post[4], rr[16];
#pragma unroll
        for (int i = 0; i < 4; ++i)  pre[i]  = red[i]     * inv * s0 + basep[i];
#pragma unroll
        for (int i = 0; i < 4; ++i)  post[i] = red[4 + i] * inv * s1 + basep[4 + i];
#pragma unroll
        for (int k = 0; k < 16; ++k) rr[k]   = red[8 + k] * inv * s2 + basep[8 + k];

        // softmax (stable) -> hp_s (consumed in-block)
        const float mx = fmaxf(fmaxf(pre[0], pre[1]), fmaxf(pre[2], pre[3]));
        float e[4], es = 0.f;
#pragma unroll
        for (int i = 0; i < 4; ++i) { e[i] = expf(pre[i] - mx); es += e[i]; }
        const float esr = 1.0f / es;
#pragma unroll
        for (int i = 0; i < 4; ++i) hp_s[i] = e[i] * esr;

        // sigmoid -> post_mix_cur
        float4 pmv = make_float4(1.f/(1.f+expf(-post[0])), 1.f/(1.f+expf(-post[1])),
                                 1.f/(1.f+expf(-post[2])), 1.f/(1.f+expf(-post[3])));
        *(float4*)(post_mix + (size_t)b * 4) = pmv;

        // Sinkhorn-Knopp, 10 iters (reciprocal-multiply, verified round 5)
        float M[16];
#pragma unroll
        for (int k = 0; k < 16; ++k) M[k] = expf(rr[k]);
#pragma unroll 1
        for (int it = 0; it < 10; ++it) {
#pragma unroll
            for (int i = 0; i < 4; ++i) {
                const float rs = 1.0f /
                    (M[i*4+0] + M[i*4+1] + M[i*4+2] + M[i*4+3] + 1e-6f);
#pragma unroll
                for (int j = 0; j < 4; ++j) M[i*4+j] *= rs;
            }
#pragma unroll
            for (int j = 0; j < 4; ++j) {
                const float cs = 1.0f /
                    (M[j] + M[4+j] + M[8+j] + M[12+j] + 1e-6f);
#pragma unroll
                for (int i = 0; i < 4; ++i) M[i*4+j] *= cs;
            }
        }
#pragma unroll
        for (int m4 = 0; m4 < 4; ++m4)
            *(float4*)(comb_out + (size_t)b * 16 + m4 * 4) =
                make_float4(M[4*m4+0], M[4*m4+1], M[4*m4+2], M[4*m4+3]);
    }
    __syncthreads();

    // layer_input[b,:] = sum_i hp[i] * res_cur[b,i,:]
    const float h0 = hp_s[0], h1 = hp_s[1], h2 = hp_s[2], h3 = hp_s[3];
    const float* rp = res_cur + (size_t)b * (MULT * HIDDEN);
    float* op = layer_in + (size_t)b * HIDDEN;
#pragma unroll
    for (int c = 0; c < 4; ++c) {
        const int c4 = (tid + c * 256) * 4;   // float element offset, 0..4092
        const float4 v0 = *(const float4*)(rp + 0 * HIDDEN + c4);
        const float4 v1 = *(const float4*)(rp + 1 * HIDDEN + c4);
        const float4 v2 = *(const float4*)(rp + 2 * HIDDEN + c4);
        const float4 v3 = *(const float4*)(rp + 3 * HIDDEN + c4);
        float4 o;
        o.x = h0*v0.x + h1*v1.x + h2*v2.x + h3*v3.x;
        o.y = h0*v0.y + h1*v1.y + h2*v2.y + h3*v3.y;
        o.z = h0*v0.z + h1*v1.z + h2*v2.z + h3*v3.z;
        o.w = h0*v0.w + h1*v1.w + h2*v2.w + h3*v3.w;
        *(float4*)(op + c4) = o;
    }
}

extern "C" void kernel_launch(void* const* d_in, const int* in_sizes, int n_in,
                              void* d_out, int out_size, void* d_ws, size_t ws_size,
                              hipStream_t stream) {
    const float* x_prev    = (const float*)d_in[0];
    const float* res_prev  = (const float*)d_in[1];
    const float* pm_prev   = (const float*)d_in[2];
    const float* comb_prev = (const float*)d_in[3];
    const float* fn        = (const float*)d_in[4];
    const float* base      = (const float*)d_in[5];
    const float* scale     = (const float*)d_in[6];

    float* out = (float*)d_out;
    float* res_cur  = out;                                   // 4096*4*4096
    float* post_mix = out + 67108864;                        // 4096*4
    float* comb_out = out + 67108864 + 16384;                // 4096*16
    float* layer_in = out + 67108864 + 16384 + 65536;        // 4096*4096

    float* ws = (float*)d_ws;
    float* fnT     = ws;                                     // 393,216 floats
    float* part_lg = ws + 393216;                            // 8*4096*24 = 786,432
    float* part_sq = ws + 393216 + 786432;                   // 8*4096   =  32,768

    k_transpose_fn<<<HCD / 256, 256, 0, stream>>>(fn, fnT);
    k_main<<<(BB / ROWS) * HSPLIT, KA_THREADS, 0, stream>>>(
        x_prev, res_prev, pm_prev, comb_prev, fnT, res_cur, part_lg, part_sq);
    k_post<<<BB, 256, 0, stream>>>(part_lg, part_sq, base, scale, res_cur,
                                   post_mix, comb_out, layer_in);
}